// Round 6
// baseline (89.961 us; speedup 1.0000x reference)
//
#include <hip/hip_runtime.h>
#include <hip/hip_bf16.h>

// DiceActor fused forward, MI355X (gfx950).
// out layout (f32): action[B*32] | pretanh[B*32] | log_prob[B] | pretanh_log_prob[B]
//
// R6 structure: ZERO __syncthreads. Each wave independently owns 16 batch
// rows end-to-end. W_bb / head fragments streamed from the packed L2-hot
// table (all waves read the same 96 KB in the same order -> L1/L2 hits).
// The backbone->head fragment transpose goes through a wave-PRIVATE 2x2KB
// LDS ping-pong (in-order DS + s_waitcnt lgkmcnt(0), no barrier).
// Regs ~100 natural -> launch_bounds(256,4) caps at 128 without starving
// (R4's failure anchor -- 64 persistent wf regs -- is gone).

#define B_TOTAL 262144
#define OBS_D   128
#define LAT     256
#define ACT     32

typedef __attribute__((ext_vector_type(8))) short bf16x8;   // 8 bf16 in 4 VGPRs
typedef __attribute__((ext_vector_type(4))) float f32x4;

__device__ __forceinline__ unsigned short f2bf(float x) {
  __hip_bfloat16 h = __float2bfloat16(x);
  return __builtin_bit_cast(unsigned short, h);
}

__device__ __forceinline__ float ftanh(float x) {
  float ax = fabsf(x);
  float e  = __expf(-2.f * ax);
  float y  = (1.f - e) / (1.f + e);
  return x < 0.f ? -y : y;
}

// ---------------------------------------------------------------------------
// Prep kernel: pack weights as bf16 into d_ws (layout unchanged since R3).
//  region A [0, 65536) bytes: W_bb B-fragments:
//    elem = g*8192 + (t*4+s)*512 + lane*8 + j      (g = 64-col group 0..3)
//    value = bf16( W_bb[k = s*32 + (lane>>4)*8 + j][n = g*64 + t*16 + (lane&15)] )
//  region B [65536, 98304) bytes: head B-fragments:
//    elem = 32768 + ((s*4+u)*64 + lane)*8 + j      (s = k-slice 0..7)
//    value = Wh[n = u*16 + (lane&15)][k = s*32 + (lane>>4)*8 + j]
//    where Wh[n][k]: n<32 -> Wmu[k][n], else Wsg[k][n-32]
// ---------------------------------------------------------------------------
__global__ void dice_prep(const float* __restrict__ Wbb,
                          const float* __restrict__ Wmu,
                          const float* __restrict__ Wsg,
                          unsigned short* __restrict__ wpack) {
  int tid = blockIdx.x * 256 + threadIdx.x;      // 192*256 = 49152 exactly
  if (tid < 32768) {
    int g    = tid >> 13;
    int rem  = tid & 8191;
    int f    = rem >> 9;
    int lane = (rem >> 3) & 63;
    int j    = rem & 7;
    int t = f >> 2, s = f & 3;
    int k = s * 32 + (lane >> 4) * 8 + j;
    int n = g * 64 + t * 16 + (lane & 15);
    wpack[tid] = f2bf(Wbb[k * LAT + n]);
  } else {
    int i    = tid - 32768;                      // [0, 16384)
    int f    = i >> 9;                           // frag 0..31 = s*4+u
    int lane = (i >> 3) & 63;
    int j    = i & 7;
    int s = f >> 2, u = f & 3;
    int n = u * 16 + (lane & 15);
    int k = s * 32 + (lane >> 4) * 8 + j;
    float v = (n < 32) ? Wmu[k * ACT + n] : Wsg[k * ACT + (n - 32)];
    wpack[32768 + i] = f2bf(v);
  }
}

// ---------------------------------------------------------------------------
// Main kernel: 256 threads = 4 independent waves, 16 rows each, grid 4096.
// LDS: 4 waves x 2 x 2KB ping-pong = 16 KB -> occupancy VGPR-bound only.
// ---------------------------------------------------------------------------
__global__ __launch_bounds__(256, 4) void dice_main(
    const float* __restrict__ obs, const float* __restrict__ noise,
    const unsigned short* __restrict__ wpack,
    const float* __restrict__ b_bb, const float* __restrict__ b_mu,
    const float* __restrict__ b_sg, float* __restrict__ out) {

  __shared__ __align__(16) unsigned char s_t[16384];

  const int tid  = threadIdx.x;
  const int wave = tid >> 6, lane = tid & 63;
  const int lrow = lane & 15, lgrp = lane >> 4;
  const int row0 = (blockIdx.x * 4 + wave) * 16;    // this wave's 16 rows
  unsigned char* my = s_t + wave * 4096;            // wave-private ping-pong

  // ---- obs A-fragments direct from global (32B contiguous per lane),
  //      f32 -> bf16 in-register. Issued first: HBM latency hides under
  //      the L2 W-fragment streams below. ----
  bf16x8 a[4];
  {
    const float* ap = obs + (size_t)(row0 + lrow) * OBS_D + lgrp * 8;
#pragma unroll
    for (int s = 0; s < 4; ++s) {
      float4 v0 = *(const float4*)(ap + s * 32);
      float4 v1 = *(const float4*)(ap + s * 32 + 4);
      bf16x8 t;
      t[0] = (short)f2bf(v0.x); t[1] = (short)f2bf(v0.y);
      t[2] = (short)f2bf(v0.z); t[3] = (short)f2bf(v0.w);
      t[4] = (short)f2bf(v1.x); t[5] = (short)f2bf(v1.y);
      t[6] = (short)f2bf(v1.z); t[7] = (short)f2bf(v1.w);
      a[s] = t;
    }
  }

  const bf16x8* hb = (const bf16x8*)(wpack + 32768);
  f32x4 acc2[4];
#pragma unroll
  for (int u = 0; u < 4; ++u) acc2[u] = (f32x4)(0.f);

  // ---- fused backbone + head over 4 latent col-groups of 64 ----
#pragma unroll
  for (int cg = 0; cg < 4; ++cg) {
    unsigned char* buf = my + (cg & 1) * 2048;      // ping-pong: no RAW hazard
    const bf16x8* wp = (const bf16x8*)wpack + cg * 1024 + lane;

    f32x4 hacc[4];
#pragma unroll
    for (int t = 0; t < 4; ++t) hacc[t] = (f32x4)(0.f);
#pragma unroll
    for (int t = 0; t < 4; ++t)
#pragma unroll
      for (int s = 0; s < 4; ++s)
        hacc[t] = __builtin_amdgcn_mfma_f32_16x16x32_bf16(a[s], wp[(t * 4 + s) * 64], hacc[t], 0, 0, 0);

    // bias + relu + bf16 -> wave-private LDS (swizzle ((row&12)<<3):
    // conflict-free for both the b16 writes and the b128 reads)
#pragma unroll
    for (int t = 0; t < 4; ++t) {
      float bb = b_bb[cg * 64 + t * 16 + lrow];
#pragma unroll
      for (int r = 0; r < 4; ++r) {
        int row_l = lgrp * 4 + r;
        float v = fmaxf(hacc[t][r] + bb, 0.f);
        int byte = row_l * 128 + ((t * 32 + lrow * 2) ^ ((row_l & 12) << 3));
        *(unsigned short*)(buf + byte) = f2bf(v);
      }
    }
    // wave-private: drain DS writes, no __syncthreads needed
    asm volatile("s_waitcnt lgkmcnt(0)" ::: "memory");

#pragma unroll
    for (int ks = 0; ks < 2; ++ks) {
      int byte = lrow * 128 + (((ks * 32 + lgrp * 8) * 2) ^ ((lrow & 12) << 3));
      bf16x8 haf = *(const bf16x8*)(buf + byte);
#pragma unroll
      for (int u = 0; u < 4; ++u)
        acc2[u] = __builtin_amdgcn_mfma_f32_16x16x32_bf16(haf, hb[((cg * 2 + ks) * 4 + u) * 64 + lane], acc2[u], 0, 0, 0);
    }
    asm volatile("" ::: "memory");   // keep next cg's DS writes after these reads
  }

  // ---- epilogue (acc2: u0=mu[0:16), u1=mu[16:32), u2=ls[0:16), u3=ls[16:32)) ----
  const float bmu0 = b_mu[lrow], bmu1 = b_mu[lrow + 16];
  const float bsg0 = b_sg[lrow], bsg1 = b_sg[lrow + 16];
  float* out_act = out;
  float* out_pre = out + (size_t)B_TOTAL * ACT;
  float* out_lp  = out + 2 * (size_t)B_TOTAL * ACT;
  float* out_plp = out_lp + B_TOTAL;

  float s1v[4], s2v[4];
#pragma unroll
  for (int r = 0; r < 4; ++r) {
    int row = row0 + lgrp * 4 + r;
    float mu0 = fminf(fmaxf(acc2[0][r] + bmu0, -7.f), 7.f);
    float mu1 = fminf(fmaxf(acc2[1][r] + bmu1, -7.f), 7.f);
    float ls0 = fminf(fmaxf(acc2[2][r] + bsg0, -2.f), 5.f);
    float ls1 = fminf(fmaxf(acc2[3][r] + bsg1, -2.f), 5.f);
    float n0 = noise[(size_t)row * ACT + lrow];
    float n1 = noise[(size_t)row * ACT + lrow + 16];
    float sp0 = __expf(0.5f * ls0), sp1 = __expf(0.5f * ls1);
    float p0 = fmaf(sp0, n0, mu0), p1 = fmaf(sp1, n1, mu1);
    float a0 = ftanh(p0), a1 = ftanh(p1);
    // (pretanh-mu)^2/std == n^2 analytically
    float t1 = fmaf(n0, n0, ls0) + fmaf(n1, n1, ls1);
    float t2 = __logf(1.f - a0 * a0 + 1e-6f) + __logf(1.f - a1 * a1 + 1e-6f);
    out_act[(size_t)row * ACT + lrow]      = a0;
    out_act[(size_t)row * ACT + lrow + 16] = a1;
    out_pre[(size_t)row * ACT + lrow]      = p0;
    out_pre[(size_t)row * ACT + lrow + 16] = p1;
    s1v[r] = t1;
    s2v[r] = t2;
  }
  // 16-lane butterfly: every lane in a 16-group ends with full row sums
#pragma unroll
  for (int m = 1; m < 16; m <<= 1) {
#pragma unroll
    for (int r = 0; r < 4; ++r) {
      s1v[r] += __shfl_xor(s1v[r], m, 64);
      s2v[r] += __shfl_xor(s2v[r], m, 64);
    }
  }
  if (lrow < 4) {
    int r = lrow;
    float s1 = (r == 0) ? s1v[0] : (r == 1) ? s1v[1] : (r == 2) ? s1v[2] : s1v[3];
    float s2 = (r == 0) ? s2v[0] : (r == 1) ? s2v[1] : (r == 2) ? s2v[2] : s2v[3];
    int row = row0 + lgrp * 4 + r;
    float plp = -0.5f * s1 - 29.406033062549525f;   // 0.5*32*log(2*pi)
    out_plp[row] = plp;
    out_lp[row]  = plp - s2;
  }
}

extern "C" void kernel_launch(void* const* d_in, const int* in_sizes, int n_in,
                              void* d_out, int out_size, void* d_ws, size_t ws_size,
                              hipStream_t stream) {
  const float* obs = (const float*)d_in[0];
  const float* noi = (const float*)d_in[1];
  const float* Wbb = (const float*)d_in[2];
  const float* bbb = (const float*)d_in[3];
  const float* Wmu = (const float*)d_in[4];
  const float* bmu = (const float*)d_in[5];
  const float* Wsg = (const float*)d_in[6];
  const float* bsg = (const float*)d_in[7];
  unsigned short* wpack = (unsigned short*)d_ws;   // needs 98304 bytes

  hipLaunchKernelGGL(dice_prep, dim3(192), dim3(256), 0, stream, Wbb, Wmu, Wsg, wpack);
  hipLaunchKernelGGL(dice_main, dim3(B_TOTAL / 64), dim3(256), 0, stream,
                     obs, noi, wpack, bbb, bmu, bsg, (float*)d_out);
}